// Round 3
// baseline (123.747 us; speedup 1.0000x reference)
//
#include <hip/hip_runtime.h>
#include <math.h>

#define LOG2E 1.4426950408889634f

// ---------------------------------------------------------------------------
// Kernel 1: build zaz[i] = {za_i, (float)Z_i} in ws (Z in [1,95)) and zero the
// output (harness poisons d_out with 0xAA before every timed replay).
// za = Z^|a_exp| computed identically to the reference path.
// ---------------------------------------------------------------------------
__global__ void __launch_bounds__(256)
zbl_prep(const int* __restrict__ Z, const float* __restrict__ a_exp,
         float2* __restrict__ zaz, float* __restrict__ out,
         int n_atoms, int out_n) {
    int i = blockIdx.x * blockDim.x + threadIdx.x;
    float aexp = fabsf(a_exp[0]);
    if (i < n_atoms) {
        float zf = (float)Z[i];
        float za = exp2f(aexp * __log2f(zf));
        zaz[i] = make_float2(za, zf);
    }
    if (i < out_n) out[i] = 0.0f;
}

// ---------------------------------------------------------------------------
// Kernel 2: 8 pairs per thread. Streaming loads are dwordx4 (2 per array);
// j-side gathers are unconditional float2 loads from the 800 KB L2-resident
// zaz table; i-side gathers are PREDICATED on run boundaries (idx_i sorted →
// ~3% active lanes for q>=1, so the TA processes almost no i-side addresses).
// Segmented reduction:
//   - thread-local run combine (interior runs commit directly; with sorted
//     keys a run bounded inside the thread is the segment's only writer),
//   - wave-64 segmented inclusive scan over the per-thread tail runs,
//   - boundary-correct commits (first run patched with prev lane's scanned c).
// ---------------------------------------------------------------------------
__global__ void __launch_bounds__(256)
zbl_pairs8(const float* __restrict__ dist, const float* __restrict__ cut,
           const int* __restrict__ idx_i, const int* __restrict__ idx_j,
           const float2* __restrict__ zaz,
           const float* __restrict__ a_coef,
           const float* __restrict__ phi_c, const float* __restrict__ phi_e,
           const float* __restrict__ ke, const float* __restrict__ d2a,
           const float* __restrict__ e2m,
           float* __restrict__ out, int n) {
    // Wave-uniform parameters (scalar loads).
    float inv_ac = __fdividef(1.0f, fabsf(a_coef[0]));
    float c0 = fabsf(phi_c[0]), c1 = fabsf(phi_c[1]),
          c2 = fabsf(phi_c[2]), c3 = fabsf(phi_c[3]);
    float cnorm = __fdividef(1.0f, c0 + c1 + c2 + c3);
    c0 *= cnorm; c1 *= cnorm; c2 *= cnorm; c3 *= cnorm;
    // exp(-e*x) = exp2(-(e*log2e)*x)
    float e0 = fabsf(phi_e[0]) * LOG2E, e1 = fabsf(phi_e[1]) * LOG2E,
          e2 = fabsf(phi_e[2]) * LOG2E, e3 = fabsf(phi_e[3]) * LOG2E;
    float scale = ke[0] * e2m[0] * __fdividef(1.0f, d2a[0]);

    int t   = threadIdx.x;
    int gid = blockIdx.x * blockDim.x + t;
    int p0  = gid * 8;

    int   k[8];
    float v[8];

    if (p0 + 7 < n) {
        // full 8-pair path: dwordx4 streaming loads
        const float4* dist4 = (const float4*)dist;
        const float4* cut4  = (const float4*)cut;
        const int4*   ii4   = (const int4*)idx_i;
        const int4*   jj4   = (const int4*)idx_j;
        float4 dA = dist4[2 * gid], dB = dist4[2 * gid + 1];
        float4 cA = cut4[2 * gid],  cB = cut4[2 * gid + 1];
        int4   iA = ii4[2 * gid],   iB = ii4[2 * gid + 1];
        int4   jA = jj4[2 * gid],   jB = jj4[2 * gid + 1];

        k[0] = iA.x; k[1] = iA.y; k[2] = iA.z; k[3] = iA.w;
        k[4] = iB.x; k[5] = iB.y; k[6] = iB.z; k[7] = iB.w;
        int j[8] = { jA.x, jA.y, jA.z, jA.w, jB.x, jB.y, jB.z, jB.w };
        float d[8] = { dA.x, dA.y, dA.z, dA.w, dB.x, dB.y, dB.z, dB.w };
        float cu[8] = { cA.x, cA.y, cA.z, cA.w, cB.x, cB.y, cB.z, cB.w };

        // j-side gathers: 8 unconditional float2 loads (independent, pipelined)
        float2 gj[8];
        #pragma unroll
        for (int q = 0; q < 8; ++q) gj[q] = zaz[j[q]];

        // i-side gathers: predicated on run boundaries (~3% active lanes q>=1)
        float za_i[8], zf_i[8];
        {
            float2 g = zaz[k[0]];
            za_i[0] = g.x; zf_i[0] = g.y;
        }
        #pragma unroll
        for (int q = 1; q < 8; ++q) {
            if (k[q] != k[q - 1]) {
                float2 g = zaz[k[q]];
                za_i[q] = g.x; zf_i[q] = g.y;
            } else {
                za_i[q] = za_i[q - 1]; zf_i[q] = zf_i[q - 1];
            }
        }

        #pragma unroll
        for (int q = 0; q < 8; ++q) {
            float arg = d[q] * (za_i[q] + gj[q].x) * inv_ac;
            float phi = c0 * exp2f(-e0 * arg) + c1 * exp2f(-e1 * arg)
                      + c2 * exp2f(-e2 * arg) + c3 * exp2f(-e3 * arg);
            v[q] = scale * zf_i[q] * gj[q].y * phi * cu[q]
                 * __fdividef(1.0f, d[q]);
        }
    } else {
        // tail: scalar path; missing slots duplicate the previous key with
        // v=0 so they merge into the tail run harmlessly (keys stay sorted).
        #pragma unroll
        for (int q = 0; q < 8; ++q) {
            int p = p0 + q;
            if (p < n) {
                int ki = idx_i[p], jj = idx_j[p];
                float2 gi = zaz[ki], gjv = zaz[jj];
                float dd = dist[p];
                float arg = dd * (gi.x + gjv.x) * inv_ac;
                float phi = c0 * exp2f(-e0 * arg) + c1 * exp2f(-e1 * arg)
                          + c2 * exp2f(-e2 * arg) + c3 * exp2f(-e3 * arg);
                k[q] = ki;
                v[q] = scale * gi.y * gjv.y * phi * cut[p]
                     * __fdividef(1.0f, dd);
            } else {
                k[q] = (q > 0) ? k[q - 1] : -1;
                v[q] = 0.0f;
            }
        }
    }

    // --- thread-local run combine (unrolled, compile-time indices only) ---
    float run = v[0];
    float firstRun = 0.0f;
    bool  firstEnds = false;
    int   runStart = 0;
    #pragma unroll
    for (int q = 1; q < 8; ++q) {
        if (k[q] == k[q - 1]) {
            run += v[q];
        } else {
            if (runStart == 0) { firstRun = run; firstEnds = true; }
            else if (k[q - 1] >= 0) atomicAdd(out + k[q - 1], run);
            run = v[q];
            runStart = q;
        }
    }
    float c   = run;     // tail-run contribution
    int   key = k[7];    // tail-run key

    // --- wave-64 segmented inclusive scan over (key, c) ---
    int lane = t & 63;
    #pragma unroll
    for (int off = 1; off < 64; off <<= 1) {
        float ov = __shfl_up(c, (unsigned)off, 64);
        int   ok = __shfl_up(key, (unsigned)off, 64);
        if (lane >= off && ok == key) c += ov;
    }

    // Neighbor info for boundary commits.
    float prev_c   = __shfl_up(c, 1u, 64);
    int   prev_key = __shfl_up(key, 1u, 64);
    int   next_k0  = __shfl_down(k[0], 1u, 64);

    // Commit the first run if it ends inside this thread, patched with the
    // scanned contribution of preceding lanes in the same segment.
    if (k[0] >= 0 && firstEnds) {
        float tot = firstRun + ((lane > 0 && prev_key == k[0]) ? prev_c : 0.0f);
        atomicAdd(out + k[0], tot);
    }
    // Commit the tail segment at its last lane in the wave.
    bool tail = (lane == 63) || (next_k0 != key);
    if (key >= 0 && tail) atomicAdd(out + key, c);
}

extern "C" void kernel_launch(void* const* d_in, const int* in_sizes, int n_in,
                              void* d_out, int out_size, void* d_ws, size_t ws_size,
                              hipStream_t stream) {
    const int*   atomic_numbers = (const int*)  d_in[0];
    const float* distances      = (const float*)d_in[1];
    const float* cutoffs        = (const float*)d_in[2];
    const int*   idx_i          = (const int*)  d_in[3];
    const int*   idx_j          = (const int*)  d_in[4];
    const float* a_coefficient  = (const float*)d_in[5];
    const float* a_exponent     = (const float*)d_in[6];
    const float* phi_coeffs     = (const float*)d_in[7];
    const float* phi_exps       = (const float*)d_in[8];
    const float* ke             = (const float*)d_in[9];
    const float* d2a            = (const float*)d_in[10];
    const float* e2m            = (const float*)d_in[11];
    float* out = (float*)d_out;

    const int n_atoms = in_sizes[0];
    const int n_pairs = in_sizes[1];

    const int block = 256;
    const int n_threads = (n_pairs + 7) / 8;
    const int grid_pairs = (n_threads + block - 1) / block;
    const int grid_prep  = (((n_atoms > out_size) ? n_atoms : out_size) + block - 1) / block;

    // ws_size is ample (harness scratch); zaz needs 8 * n_atoms bytes.
    float2* zaz = (float2*)d_ws;
    zbl_prep<<<grid_prep, block, 0, stream>>>(
        atomic_numbers, a_exponent, zaz, out, n_atoms, out_size);
    zbl_pairs8<<<grid_pairs, block, 0, stream>>>(
        distances, cutoffs, idx_i, idx_j, zaz,
        a_coefficient, phi_coeffs, phi_exps, ke, d2a, e2m,
        out, n_pairs);
}

// Round 4
// 117.413 us; speedup vs baseline: 1.0539x; 1.0539x over previous
//
#include <hip/hip_runtime.h>
#include <math.h>

#define LOG2E 1.4426950408889634f

// ---------------------------------------------------------------------------
// Kernel 1: compress Z to uint8 in ws (Z in [1,95)) and zero the output
// (harness poisons d_out with 0xAA before every timed replay).
// ---------------------------------------------------------------------------
__global__ void __launch_bounds__(256)
zbl_prep(const int* __restrict__ Z, unsigned char* __restrict__ z8,
         float* __restrict__ out, int n_atoms, int out_n) {
    int i = blockIdx.x * blockDim.x + threadIdx.x;
    if (i < n_atoms) z8[i] = (unsigned char)Z[i];
    if (i < out_n)   out[i] = 0.0f;
}

// ---------------------------------------------------------------------------
// Kernel 2: 8 pairs per thread. Streaming loads are dwordx4 (2 per array);
// Z gathers are 1-byte loads from the 100 KB z8 table (64 atoms per cache
// line; i-side addresses are nearly wave-uniform since idx_i is sorted, so
// they cost ~1 line per instruction). za = Z^|a_exp| from a 128-entry LDS
// table. Segmented reduction:
//   - thread-local run combine (interior runs commit directly; they cannot
//     cross a thread boundary),
//   - wave-64 segmented inclusive scan over the per-thread tail runs,
//   - boundary-correct commits (first run patched with prev lane's scanned c).
// Correctness relies on idx_i being globally sorted (non-decreasing).
// ---------------------------------------------------------------------------
__global__ void __launch_bounds__(256)
zbl_pairs8(const float* __restrict__ dist, const float* __restrict__ cut,
           const int* __restrict__ idx_i, const int* __restrict__ idx_j,
           const unsigned char* __restrict__ z8,
           const float* __restrict__ a_coef, const float* __restrict__ a_exp,
           const float* __restrict__ phi_c, const float* __restrict__ phi_e,
           const float* __restrict__ ke, const float* __restrict__ d2a,
           const float* __restrict__ e2m,
           float* __restrict__ out, int n) {
    __shared__ float za_tab[128];

    // Wave-uniform parameters (scalar loads).
    float aexp   = fabsf(a_exp[0]);
    float inv_ac = __fdividef(1.0f, fabsf(a_coef[0]));
    float c0 = fabsf(phi_c[0]), c1 = fabsf(phi_c[1]),
          c2 = fabsf(phi_c[2]), c3 = fabsf(phi_c[3]);
    float cnorm = __fdividef(1.0f, c0 + c1 + c2 + c3);
    c0 *= cnorm; c1 *= cnorm; c2 *= cnorm; c3 *= cnorm;
    // exp(-e*x) = exp2(-(e*log2e)*x)
    float e0 = fabsf(phi_e[0]) * LOG2E, e1 = fabsf(phi_e[1]) * LOG2E,
          e2 = fabsf(phi_e[2]) * LOG2E, e3 = fabsf(phi_e[3]) * LOG2E;
    float scale = ke[0] * e2m[0] * __fdividef(1.0f, d2a[0]);

    int t = threadIdx.x;
    if (t < 128) za_tab[t] = (t >= 1) ? exp2f(aexp * __log2f((float)t)) : 0.0f;
    __syncthreads();

    int gid = blockIdx.x * blockDim.x + t;
    int p0  = gid * 8;

    int   k[8];
    float v[8];

    if (p0 + 7 < n) {
        // full 8-pair path: dwordx4 streaming loads
        const float4* dist4 = (const float4*)dist;
        const float4* cut4  = (const float4*)cut;
        const int4*   ii4   = (const int4*)idx_i;
        const int4*   jj4   = (const int4*)idx_j;
        float4 dA = dist4[2 * gid], dB = dist4[2 * gid + 1];
        float4 cA = cut4[2 * gid],  cB = cut4[2 * gid + 1];
        int4   iA = ii4[2 * gid],   iB = ii4[2 * gid + 1];
        int4   jA = jj4[2 * gid],   jB = jj4[2 * gid + 1];

        k[0] = iA.x; k[1] = iA.y; k[2] = iA.z; k[3] = iA.w;
        k[4] = iB.x; k[5] = iB.y; k[6] = iB.z; k[7] = iB.w;
        int j[8] = { jA.x, jA.y, jA.z, jA.w, jB.x, jB.y, jB.z, jB.w };
        float d[8]  = { dA.x, dA.y, dA.z, dA.w, dB.x, dB.y, dB.z, dB.w };
        float cu[8] = { cA.x, cA.y, cA.z, cA.w, cB.x, cB.y, cB.z, cB.w };

        // byte gathers: 8 i-side (near-uniform lines) + 8 j-side (random),
        // all independent so the TA/L2 pipeline stays full
        int zi[8], zj[8];
        #pragma unroll
        for (int q = 0; q < 8; ++q) zi[q] = (int)z8[k[q]];
        #pragma unroll
        for (int q = 0; q < 8; ++q) zj[q] = (int)z8[j[q]];

        #pragma unroll
        for (int q = 0; q < 8; ++q) {
            float arg = d[q] * (za_tab[zi[q]] + za_tab[zj[q]]) * inv_ac;
            float phi = c0 * exp2f(-e0 * arg) + c1 * exp2f(-e1 * arg)
                      + c2 * exp2f(-e2 * arg) + c3 * exp2f(-e3 * arg);
            v[q] = scale * (float)(zi[q] * zj[q]) * phi * cu[q]
                 * __fdividef(1.0f, d[q]);
        }
    } else {
        // tail: scalar path; missing slots duplicate the previous key with
        // v=0 so they merge into the tail run harmlessly (keys stay sorted).
        #pragma unroll
        for (int q = 0; q < 8; ++q) {
            int p = p0 + q;
            if (p < n) {
                int ki = idx_i[p], jj = idx_j[p];
                int zi = (int)z8[ki], zj = (int)z8[jj];
                float dd = dist[p];
                float arg = dd * (za_tab[zi] + za_tab[zj]) * inv_ac;
                float phi = c0 * exp2f(-e0 * arg) + c1 * exp2f(-e1 * arg)
                          + c2 * exp2f(-e2 * arg) + c3 * exp2f(-e3 * arg);
                k[q] = ki;
                v[q] = scale * (float)(zi * zj) * phi * cut[p]
                     * __fdividef(1.0f, dd);
            } else {
                k[q] = (q > 0) ? k[q - 1] : -1;
                v[q] = 0.0f;
            }
        }
    }

    // --- thread-local run combine (unrolled, compile-time indices only) ---
    float run = v[0];
    float firstRun = 0.0f;
    bool  firstEnds = false;
    int   runStart = 0;
    #pragma unroll
    for (int q = 1; q < 8; ++q) {
        if (k[q] == k[q - 1]) {
            run += v[q];
        } else {
            if (runStart == 0) { firstRun = run; firstEnds = true; }
            else if (k[q - 1] >= 0) atomicAdd(out + k[q - 1], run);
            run = v[q];
            runStart = q;
        }
    }
    float c   = run;     // tail-run contribution
    int   key = k[7];    // tail-run key

    // --- wave-64 segmented inclusive scan over (key, c) ---
    int lane = t & 63;
    #pragma unroll
    for (int off = 1; off < 64; off <<= 1) {
        float ov = __shfl_up(c, (unsigned)off, 64);
        int   ok = __shfl_up(key, (unsigned)off, 64);
        if (lane >= off && ok == key) c += ov;
    }

    // Neighbor info for boundary commits.
    float prev_c   = __shfl_up(c, 1u, 64);
    int   prev_key = __shfl_up(key, 1u, 64);
    int   next_k0  = __shfl_down(k[0], 1u, 64);

    // Commit the first run if it ends inside this thread, patched with the
    // scanned contribution of preceding lanes in the same segment.
    if (k[0] >= 0 && firstEnds) {
        float tot = firstRun + ((lane > 0 && prev_key == k[0]) ? prev_c : 0.0f);
        atomicAdd(out + k[0], tot);
    }
    // Commit the tail segment at its last lane in the wave.
    bool tail = (lane == 63) || (next_k0 != key);
    if (key >= 0 && tail) atomicAdd(out + key, c);
}

extern "C" void kernel_launch(void* const* d_in, const int* in_sizes, int n_in,
                              void* d_out, int out_size, void* d_ws, size_t ws_size,
                              hipStream_t stream) {
    const int*   atomic_numbers = (const int*)  d_in[0];
    const float* distances      = (const float*)d_in[1];
    const float* cutoffs        = (const float*)d_in[2];
    const int*   idx_i          = (const int*)  d_in[3];
    const int*   idx_j          = (const int*)  d_in[4];
    const float* a_coefficient  = (const float*)d_in[5];
    const float* a_exponent     = (const float*)d_in[6];
    const float* phi_coeffs     = (const float*)d_in[7];
    const float* phi_exps       = (const float*)d_in[8];
    const float* ke             = (const float*)d_in[9];
    const float* d2a            = (const float*)d_in[10];
    const float* e2m            = (const float*)d_in[11];
    float* out = (float*)d_out;

    const int n_atoms = in_sizes[0];
    const int n_pairs = in_sizes[1];

    const int block = 256;
    const int n_threads = (n_pairs + 7) / 8;
    const int grid_pairs = (n_threads + block - 1) / block;
    const int grid_prep  = (((n_atoms > out_size) ? n_atoms : out_size) + block - 1) / block;

    // ws_size is ample (harness scratch); z8 needs only n_atoms bytes.
    unsigned char* z8 = (unsigned char*)d_ws;
    zbl_prep<<<grid_prep, block, 0, stream>>>(
        atomic_numbers, z8, out, n_atoms, out_size);
    zbl_pairs8<<<grid_pairs, block, 0, stream>>>(
        distances, cutoffs, idx_i, idx_j, z8,
        a_coefficient, a_exponent, phi_coeffs, phi_exps, ke, d2a, e2m,
        out, n_pairs);
}